// Round 1
// baseline (5300.320 us; speedup 1.0000x reference)
//
#include <hip/hip_runtime.h>
#include <hip/hip_bf16.h>
#include <cstdint>

#define BDIM 768
#define HN 12
#define HDIM 64
#define SEQ 2048
#define BATCH 4

// ---------------- Tiled fp32 GEMM + bias: C[M,N] = A[M,K] @ W[K,N] + bias ----
// 64x64 block tile, BK=16, 256 threads, 4x4 register tile per thread.
__global__ __launch_bounds__(256) void gemm_bias_f32(
    const float* __restrict__ A, const float* __restrict__ W,
    const float* __restrict__ bias, float* __restrict__ C,
    int M, int N, int K)
{
    __shared__ float As[16][68];   // stride 68 floats (272B, 16B-aligned rows)
    __shared__ float Bs[16][64];

    const int tid = threadIdx.x;
    const int tx  = tid & 15;      // col group 0..15
    const int ty  = tid >> 4;      // row group 0..15
    const int n0  = blockIdx.x * 64;
    const int m0  = blockIdx.y * 64;

    const int a_k = tid & 15;      // k within tile
    const int a_m = tid >> 4;      // base row (+16*i)
    const int b_n = tid & 63;
    const int b_k = tid >> 6;      // +4*i

    float c[4][4] = {};

    for (int k0 = 0; k0 < K; k0 += 16) {
        #pragma unroll
        for (int i = 0; i < 4; ++i)
            As[a_k][a_m + 16 * i] =
                A[(size_t)(m0 + a_m + 16 * i) * K + k0 + a_k];
        #pragma unroll
        for (int i = 0; i < 4; ++i)
            Bs[b_k + 4 * i][b_n] =
                W[(size_t)(k0 + b_k + 4 * i) * N + n0 + b_n];
        __syncthreads();

        #pragma unroll
        for (int kk = 0; kk < 16; ++kk) {
            const float4 av = *(const float4*)&As[kk][ty * 4];
            const float4 bv = *(const float4*)&Bs[kk][tx * 4];
            const float aa[4] = {av.x, av.y, av.z, av.w};
            const float bb[4] = {bv.x, bv.y, bv.z, bv.w};
            #pragma unroll
            for (int i = 0; i < 4; ++i)
                #pragma unroll
                for (int j = 0; j < 4; ++j)
                    c[i][j] += aa[i] * bb[j];
        }
        __syncthreads();
    }

    #pragma unroll
    for (int i = 0; i < 4; ++i) {
        const int m = m0 + ty * 4 + i;
        #pragma unroll
        for (int j = 0; j < 4; ++j) {
            const int n = n0 + tx * 4 + j;
            C[(size_t)m * N + n] = c[i][j] + bias[n];
        }
    }
}

// ---------------- Causal attention: one block per (b, h, q) ------------------
// qkv: [B, S, 3*D] fp32 (Q at 0, K at D, V at 2D within last dim)
// yatt: [B, S, D] fp32
__global__ __launch_bounds__(256) void attn_f32(
    const float* __restrict__ qkv, float* __restrict__ yatt)
{
    const int q   = blockIdx.x & (SEQ - 1);
    const int bh  = blockIdx.x >> 11;   // SEQ = 2048 = 2^11
    const int h   = bh % HN;
    const int b   = bh / HN;
    const int tid  = threadIdx.x;
    const int lane = tid & 63;
    const int grp  = tid >> 6;

    __shared__ float qs[HDIM];
    __shared__ float sc[SEQ];
    __shared__ float red[4];
    __shared__ float pv[4][HDIM];

    const size_t rowstride = 3 * BDIM;
    const float* qptr = qkv + ((size_t)(b * SEQ + q)) * rowstride + h * HDIM;
    if (tid < HDIM) qs[tid] = qptr[tid] * 0.125f;   // 1/sqrt(64)
    __syncthreads();

    // ---- scores: sc[k] = (q . k) * scale, k in [0, q] ----
    const float* kbase = qkv + (size_t)b * SEQ * rowstride + BDIM + h * HDIM;
    float lmax = -3.4e38f;
    for (int k = tid; k <= q; k += 256) {
        const float* kp = kbase + (size_t)k * rowstride;
        float acc = 0.f;
        #pragma unroll
        for (int d = 0; d < HDIM; d += 4) {
            const float4 kv = *(const float4*)(kp + d);
            acc += qs[d] * kv.x + qs[d + 1] * kv.y
                 + qs[d + 2] * kv.z + qs[d + 3] * kv.w;
        }
        sc[k] = acc;
        lmax  = fmaxf(lmax, acc);
    }

    // ---- block max ----
    #pragma unroll
    for (int o = 32; o; o >>= 1) lmax = fmaxf(lmax, __shfl_xor(lmax, o));
    if (lane == 0) red[grp] = lmax;
    __syncthreads();
    const float m = fmaxf(fmaxf(red[0], red[1]), fmaxf(red[2], red[3]));
    __syncthreads();   // red is reused below

    // ---- exp + sum ----
    float lsum = 0.f;
    for (int k = tid; k <= q; k += 256) {
        const float p = __expf(sc[k] - m);
        sc[k] = p;
        lsum += p;
    }
    #pragma unroll
    for (int o = 32; o; o >>= 1) lsum += __shfl_xor(lsum, o);
    if (lane == 0) red[grp] = lsum;
    __syncthreads();   // also orders sc[] probability writes before PV reads
    const float inv = 1.f / (red[0] + red[1] + red[2] + red[3]);

    // ---- PV: 4 key-groups x 64 lanes (lane = head dim) ----
    const float* vbase = qkv + (size_t)b * SEQ * rowstride + 2 * BDIM
                       + h * HDIM + lane;
    float acc = 0.f;
    for (int k = grp; k <= q; k += 4)
        acc += sc[k] * vbase[(size_t)k * rowstride];
    pv[grp][lane] = acc;
    __syncthreads();

    if (tid < HDIM) {
        const float r = (pv[0][tid] + pv[1][tid] + pv[2][tid] + pv[3][tid]) * inv;
        yatt[((size_t)(b * SEQ + q)) * BDIM + h * HDIM + tid] = r;
    }
}

// ---------------- launch -----------------------------------------------------
extern "C" void kernel_launch(void* const* d_in, const int* in_sizes, int n_in,
                              void* d_out, int out_size, void* d_ws, size_t ws_size,
                              hipStream_t stream)
{
    const float* x      = (const float*)d_in[0];
    const float* w_qkv  = (const float*)d_in[1];
    const float* b_qkv  = (const float*)d_in[2];
    const float* w_proj = (const float*)d_in[3];
    const float* b_proj = (const float*)d_in[4];
    float* out = (float*)d_out;

    float* qkv  = (float*)d_ws;                                   // [B*S, 3D]
    float* yatt = qkv + (size_t)BATCH * SEQ * 3 * BDIM;           // [B*S, D]

    const int M = BATCH * SEQ;   // 8192

    // qkv = x @ w_qkv + b_qkv
    gemm_bias_f32<<<dim3((3 * BDIM) / 64, M / 64), 256, 0, stream>>>(
        x, w_qkv, b_qkv, qkv, M, 3 * BDIM, BDIM);

    // attention per (b, h, q)
    attn_f32<<<dim3(BATCH * HN * SEQ), 256, 0, stream>>>(qkv, yatt);

    // out = yatt @ w_proj + b_proj
    gemm_bias_f32<<<dim3(BDIM / 64, M / 64), 256, 0, stream>>>(
        yatt, w_proj, b_proj, out, M, BDIM, BDIM);
}

// Round 2
// 1368.270 us; speedup vs baseline: 3.8737x; 3.8737x over previous
//
#include <hip/hip_runtime.h>
#include <hip/hip_bf16.h>
#include <cstdint>

#define BDIM 768
#define HN 12
#define HDIM 64
#define SEQ 2048
#define BATCH 4
#define ROWS (3 * BDIM)   // qkv row stride in floats

// ---------------- Tiled fp32 GEMM + bias: C[M,N] = A[M,K] @ W[K,N] + bias ----
__global__ __launch_bounds__(256) void gemm_bias_f32(
    const float* __restrict__ A, const float* __restrict__ W,
    const float* __restrict__ bias, float* __restrict__ C,
    int M, int N, int K)
{
    __shared__ float As[16][68];
    __shared__ float Bs[16][64];

    const int tid = threadIdx.x;
    const int tx  = tid & 15;
    const int ty  = tid >> 4;
    const int n0  = blockIdx.x * 64;
    const int m0  = blockIdx.y * 64;

    const int a_k = tid & 15;
    const int a_m = tid >> 4;
    const int b_n = tid & 63;
    const int b_k = tid >> 6;

    float c[4][4] = {};

    for (int k0 = 0; k0 < K; k0 += 16) {
        #pragma unroll
        for (int i = 0; i < 4; ++i)
            As[a_k][a_m + 16 * i] =
                A[(size_t)(m0 + a_m + 16 * i) * K + k0 + a_k];
        #pragma unroll
        for (int i = 0; i < 4; ++i)
            Bs[b_k + 4 * i][b_n] =
                W[(size_t)(k0 + b_k + 4 * i) * N + n0 + b_n];
        __syncthreads();

        #pragma unroll
        for (int kk = 0; kk < 16; ++kk) {
            const float4 av = *(const float4*)&As[kk][ty * 4];
            const float4 bv = *(const float4*)&Bs[kk][tx * 4];
            const float aa[4] = {av.x, av.y, av.z, av.w};
            const float bb[4] = {bv.x, bv.y, bv.z, bv.w};
            #pragma unroll
            for (int i = 0; i < 4; ++i)
                #pragma unroll
                for (int j = 0; j < 4; ++j)
                    c[i][j] += aa[i] * bb[j];
        }
        __syncthreads();
    }

    #pragma unroll
    for (int i = 0; i < 4; ++i) {
        const int m = m0 + ty * 4 + i;
        #pragma unroll
        for (int j = 0; j < 4; ++j) {
            const int n = n0 + tx * 4 + j;
            C[(size_t)m * N + n] = c[i][j] + bias[n];
        }
    }
}

// ---------------- Flash attention (fp32), one block per (b,h,q-tile) ---------
// qkv: [B, S, 3*D] fp32; yatt: [B, S, D] fp32.
// 256 threads = 16x16 grid; thread (ty,tx) owns S[ty*4+i][tx*4+j] and
// O[ty*4+i][tx*4+j]. K/V tiles of 64 staged in LDS; online softmax.
__global__ __launch_bounds__(256) void attn_flash_f32(
    const float* __restrict__ qkv, float* __restrict__ yatt)
{
    __shared__ float Qs_t[HDIM][64];   // [d][qi], pre-scaled
    __shared__ float Ks_t[HDIM][64];   // [d][kj]
    __shared__ float Vs[64][HDIM];     // [kj][d]
    __shared__ float Ps_t[64][64];     // [kj][qi]

    const int qt = (int)gridDim.x - 1 - (int)blockIdx.x;  // longest first
    const int bh = blockIdx.y;
    const int h  = bh % HN;
    const int b  = bh / HN;
    const int q0 = qt * 64;

    const int tid = threadIdx.x;
    const int tx  = tid & 15;
    const int ty  = tid >> 4;

    const float* qbase = qkv + (size_t)b * SEQ * ROWS + h * HDIM;
    const float* kbase = qbase + BDIM;
    const float* vbase = qbase + 2 * BDIM;

    // ---- stage Q tile (transposed + scaled) ----
    #pragma unroll
    for (int i = 0; i < 4; ++i) {
        const int slot = tid + i * 256;       // 0..1023
        const int r  = slot >> 4;             // q row 0..63
        const int c4 = slot & 15;             // float4 col
        const float4 v = *(const float4*)(qbase + (size_t)(q0 + r) * ROWS + c4 * 4);
        Qs_t[c4 * 4 + 0][r] = v.x * 0.125f;
        Qs_t[c4 * 4 + 1][r] = v.y * 0.125f;
        Qs_t[c4 * 4 + 2][r] = v.z * 0.125f;
        Qs_t[c4 * 4 + 3][r] = v.w * 0.125f;
    }

    float o[4][4] = {};
    float mv[4] = {-3.0e38f, -3.0e38f, -3.0e38f, -3.0e38f};
    float lv[4] = {};

    for (int kt = 0; kt <= qt; ++kt) {
        const int k0 = kt * 64;

        __syncthreads();   // prev PV done (also covers initial Q staging)

        // ---- stage K (transposed) and V tiles ----
        #pragma unroll
        for (int i = 0; i < 4; ++i) {
            const int slot = tid + i * 256;
            const int r  = slot >> 4;
            const int c4 = slot & 15;
            const float4 kv = *(const float4*)(kbase + (size_t)(k0 + r) * ROWS + c4 * 4);
            Ks_t[c4 * 4 + 0][r] = kv.x;
            Ks_t[c4 * 4 + 1][r] = kv.y;
            Ks_t[c4 * 4 + 2][r] = kv.z;
            Ks_t[c4 * 4 + 3][r] = kv.w;
            const float4 vv = *(const float4*)(vbase + (size_t)(k0 + r) * ROWS + c4 * 4);
            *(float4*)&Vs[r][c4 * 4] = vv;
        }
        __syncthreads();

        // ---- S = Q K^T (outer-product over d) ----
        float s[4][4] = {};
        #pragma unroll 8
        for (int d = 0; d < HDIM; ++d) {
            const float4 a = *(const float4*)&Qs_t[d][ty * 4];
            const float4 bq = *(const float4*)&Ks_t[d][tx * 4];
            const float aa[4] = {a.x, a.y, a.z, a.w};
            const float bb[4] = {bq.x, bq.y, bq.z, bq.w};
            #pragma unroll
            for (int i = 0; i < 4; ++i)
                #pragma unroll
                for (int j = 0; j < 4; ++j)
                    s[i][j] += aa[i] * bb[j];
        }

        // ---- causal mask on diagonal tile ----
        if (kt == qt) {
            #pragma unroll
            for (int i = 0; i < 4; ++i)
                #pragma unroll
                for (int j = 0; j < 4; ++j)
                    if (tx * 4 + j > ty * 4 + i) s[i][j] = -3.0e38f;
        }

        // ---- online softmax ----
        float rm[4], p[4][4], rs[4];
        #pragma unroll
        for (int i = 0; i < 4; ++i) {
            rm[i] = fmaxf(fmaxf(s[i][0], s[i][1]), fmaxf(s[i][2], s[i][3]));
            #pragma unroll
            for (int msk = 1; msk < 16; msk <<= 1)
                rm[i] = fmaxf(rm[i], __shfl_xor(rm[i], msk));
        }
        #pragma unroll
        for (int i = 0; i < 4; ++i) {
            const float mnew = fmaxf(mv[i], rm[i]);
            const float sc = __expf(mv[i] - mnew);
            mv[i] = mnew;
            rs[i] = 0.f;
            #pragma unroll
            for (int j = 0; j < 4; ++j) {
                p[i][j] = __expf(s[i][j] - mnew);
                rs[i] += p[i][j];
            }
            #pragma unroll
            for (int msk = 1; msk < 16; msk <<= 1)
                rs[i] += __shfl_xor(rs[i], msk);
            lv[i] = lv[i] * sc + rs[i];
            #pragma unroll
            for (int j = 0; j < 4; ++j) o[i][j] *= sc;
        }

        // ---- stage P transposed ----
        #pragma unroll
        for (int i = 0; i < 4; ++i)
            #pragma unroll
            for (int j = 0; j < 4; ++j)
                Ps_t[tx * 4 + j][ty * 4 + i] = p[i][j];
        __syncthreads();

        // ---- O += P V (outer-product over kj) ----
        #pragma unroll 8
        for (int kj = 0; kj < 64; ++kj) {
            const float4 pa = *(const float4*)&Ps_t[kj][ty * 4];
            const float4 vv = *(const float4*)&Vs[kj][tx * 4];
            const float pp[4] = {pa.x, pa.y, pa.z, pa.w};
            const float vb[4] = {vv.x, vv.y, vv.z, vv.w};
            #pragma unroll
            for (int i = 0; i < 4; ++i)
                #pragma unroll
                for (int j = 0; j < 4; ++j)
                    o[i][j] += pp[i] * vb[j];
        }
    }

    // ---- normalize + store ----
    #pragma unroll
    for (int i = 0; i < 4; ++i) {
        const float inv = 1.f / lv[i];
        float4 r;
        r.x = o[i][0] * inv; r.y = o[i][1] * inv;
        r.z = o[i][2] * inv; r.w = o[i][3] * inv;
        *(float4*)(yatt + (size_t)(b * SEQ + q0 + ty * 4 + i) * BDIM
                   + h * HDIM + tx * 4) = r;
    }
}

// ---------------- launch -----------------------------------------------------
extern "C" void kernel_launch(void* const* d_in, const int* in_sizes, int n_in,
                              void* d_out, int out_size, void* d_ws, size_t ws_size,
                              hipStream_t stream)
{
    const float* x      = (const float*)d_in[0];
    const float* w_qkv  = (const float*)d_in[1];
    const float* b_qkv  = (const float*)d_in[2];
    const float* w_proj = (const float*)d_in[3];
    const float* b_proj = (const float*)d_in[4];
    float* out = (float*)d_out;

    float* qkv  = (float*)d_ws;                                   // [B*S, 3D]
    float* yatt = qkv + (size_t)BATCH * SEQ * 3 * BDIM;           // [B*S, D]

    const int M = BATCH * SEQ;   // 8192

    gemm_bias_f32<<<dim3((3 * BDIM) / 64, M / 64), 256, 0, stream>>>(
        x, w_qkv, b_qkv, qkv, M, 3 * BDIM, BDIM);

    attn_flash_f32<<<dim3(SEQ / 64, BATCH * HN), 256, 0, stream>>>(qkv, yatt);

    gemm_bias_f32<<<dim3(BDIM / 64, M / 64), 256, 0, stream>>>(
        yatt, w_proj, b_proj, out, M, BDIM, BDIM);
}

// Round 4
// 346.079 us; speedup vs baseline: 15.3153x; 3.9536x over previous
//
#include <hip/hip_runtime.h>
#include <hip/hip_bf16.h>
#include <cstdint>

#define BDIM 768
#define HN 12
#define HDIM 64
#define SEQ 2048
#define BATCH 4
#define QR (3 * BDIM)          // qkv row stride (elements)
#define MTOT (BATCH * SEQ)     // 8192

typedef __attribute__((ext_vector_type(8))) short bfrag;   // 8 bf16 (4 VGPR)
typedef __attribute__((ext_vector_type(4))) float f32x4;

static __device__ __forceinline__ unsigned short f2bf(float f) {
    union { float f; unsigned u; } v; v.f = f;
    unsigned r = v.u + 0x7FFF + ((v.u >> 16) & 1);   // RNE
    return (unsigned short)(r >> 16);
}

static __device__ __forceinline__ void store_out(float* p, float v) { *p = v; }
static __device__ __forceinline__ void store_out(unsigned short* p, float v) { *p = f2bf(v); }

// ---------------- prep: fp32 -> bf16 flat convert ---------------------------
__global__ __launch_bounds__(256) void conv_f32_bf16(
    const float* __restrict__ in, unsigned short* __restrict__ out, int n8)
{
    const int i = blockIdx.x * 256 + threadIdx.x;
    if (i >= n8) return;
    const float4 a = ((const float4*)in)[i * 2];
    const float4 b = ((const float4*)in)[i * 2 + 1];
    bfrag o;
    o[0] = f2bf(a.x); o[1] = f2bf(a.y); o[2] = f2bf(a.z); o[3] = f2bf(a.w);
    o[4] = f2bf(b.x); o[5] = f2bf(b.y); o[6] = f2bf(b.z); o[7] = f2bf(b.w);
    ((bfrag*)out)[i] = o;
}

// ---------------- prep: [R][C] fp32 -> [C][R] bf16 transpose ----------------
__global__ __launch_bounds__(256) void transpose_f32_bf16(
    const float* __restrict__ in, unsigned short* __restrict__ out, int R, int C)
{
    __shared__ unsigned short t[64][72];
    const int tid = threadIdx.x;
    const int c0 = blockIdx.x * 64, r0 = blockIdx.y * 64;
    #pragma unroll
    for (int i = 0; i < 4; ++i) {
        const int r = (tid >> 4) + i * 16;
        const int c = (tid & 15) * 4;
        const float4 v = *(const float4*)&in[(size_t)(r0 + r) * C + c0 + c];
        t[c + 0][r] = f2bf(v.x);
        t[c + 1][r] = f2bf(v.y);
        t[c + 2][r] = f2bf(v.z);
        t[c + 3][r] = f2bf(v.w);
    }
    __syncthreads();
    #pragma unroll
    for (int i = 0; i < 2; ++i) {
        const int c = (tid >> 3) + i * 32;
        const int r = (tid & 7) * 8;
        *(bfrag*)&out[(size_t)(c0 + c) * R + r0 + r] = *(const bfrag*)&t[c][r];
    }
}

// ---------------- bf16 MFMA GEMM: C[M,N] = A[M,K] @ Bt[N,K]^T + bias --------
// 128x128 tile, BK=64, 4 waves (2x2 of 64x64), global_load_lds staging with
// pre-swizzled source, XOR-swizzled ds_read_b128 fragments.
template <typename OUTT>
__global__ __launch_bounds__(256) void gemm_mfma_bt(
    const unsigned short* __restrict__ A,   // [M][K] bf16
    const unsigned short* __restrict__ Bt,  // [N][K] bf16
    const float* __restrict__ bias,
    OUTT* __restrict__ C, int M, int N, int K)
{
    __shared__ unsigned short As[128 * 64];
    __shared__ unsigned short Bs[128 * 64];

    const int tid  = threadIdx.x;
    const int lane = tid & 63;
    const int wid  = tid >> 6;
    const int l15  = lane & 15;
    const int l4   = lane >> 4;
    const int m0 = blockIdx.y * 128;
    const int n0 = blockIdx.x * 128;
    const int wm = (wid >> 1) * 64;
    const int wn = (wid & 1) * 64;

    f32x4 acc[4][4] = {};

    for (int k0 = 0; k0 < K; k0 += 64) {
        __syncthreads();
        #pragma unroll
        for (int i = 0; i < 4; ++i) {
            const int row = wid * 32 + i * 8 + (lane >> 3);
            const int ck  = (((lane & 7) ^ (row & 7)) * 8);
            __builtin_amdgcn_global_load_lds(
                (const __attribute__((address_space(1))) void*)(A + (size_t)(m0 + row) * K + k0 + ck),
                (__attribute__((address_space(3))) void*)(As + (wid * 4 + i) * 512),
                16, 0, 0);
            __builtin_amdgcn_global_load_lds(
                (const __attribute__((address_space(1))) void*)(Bt + (size_t)(n0 + row) * K + k0 + ck),
                (__attribute__((address_space(3))) void*)(Bs + (wid * 4 + i) * 512),
                16, 0, 0);
        }
        __syncthreads();

        #pragma unroll
        for (int ks = 0; ks < 2; ++ks) {
            bfrag af[4], bfv[4];
            #pragma unroll
            for (int mi = 0; mi < 4; ++mi) {
                const int row = wm + mi * 16 + l15;
                const int ch  = (ks * 4 + l4) ^ (row & 7);
                af[mi] = *(const bfrag*)(As + row * 64 + ch * 8);
            }
            #pragma unroll
            for (int ni = 0; ni < 4; ++ni) {
                const int row = wn + ni * 16 + l15;
                const int ch  = (ks * 4 + l4) ^ (row & 7);
                bfv[ni] = *(const bfrag*)(Bs + row * 64 + ch * 8);
            }
            #pragma unroll
            for (int mi = 0; mi < 4; ++mi)
                #pragma unroll
                for (int ni = 0; ni < 4; ++ni)
                    acc[mi][ni] = __builtin_amdgcn_mfma_f32_16x16x32_bf16(
                        af[mi], bfv[ni], acc[mi][ni], 0, 0, 0);
        }
    }

    #pragma unroll
    for (int mi = 0; mi < 4; ++mi)
        #pragma unroll
        for (int ni = 0; ni < 4; ++ni) {
            const int n = n0 + wn + ni * 16 + l15;
            const float bv = bias[n];
            #pragma unroll
            for (int r = 0; r < 4; ++r) {
                const int m = m0 + wm + mi * 16 + l4 * 4 + r;
                store_out(C + (size_t)m * N + n, acc[mi][ni][r] + bv);
            }
        }
}

// ---------------- MFMA flash attention --------------------------------------
// qkv bf16 [B*S][3*768]; yatt bf16 [B*S][768].
// Block: 4 waves, QBLK=64 (16 q-rows/wave), KVBLK=64, HD=64.
__global__ __launch_bounds__(256) void attn_flash_mfma(
    const unsigned short* __restrict__ qkv, unsigned short* __restrict__ yatt)
{
    __shared__ unsigned short Ks[64 * 64];   // [k][d] swizzled
    __shared__ unsigned short Vt[64 * 64];   // [d][k] swizzled
    __shared__ unsigned short Ps[64 * 64];   // [q][k] swizzled

    const int qt = (int)gridDim.x - 1 - (int)blockIdx.x;  // longest first
    const int bh = blockIdx.y;
    const int h  = bh % HN;
    const int b  = bh / HN;
    const int q0 = qt * 64;

    const int tid  = threadIdx.x;
    const int lane = tid & 63;
    const int wid  = tid >> 6;
    const int l15  = lane & 15;
    const int l4   = lane >> 4;

    const size_t baserow = (size_t)b * SEQ;

    // Q fragments in registers (row = q0 + wid*16 + l15, k-chunks per l4)
    bfrag qf[2];
    {
        const unsigned short* qrow =
            qkv + (baserow + q0 + wid * 16 + l15) * QR + h * HDIM;
        qf[0] = *(const bfrag*)(qrow + l4 * 8);
        qf[1] = *(const bfrag*)(qrow + 32 + l4 * 8);
    }

    f32x4 acc_o[4] = {};
    float mrow[4] = {-3.0e38f, -3.0e38f, -3.0e38f, -3.0e38f};
    float lrow[4] = {};

    for (int kt = 0; kt <= qt; ++kt) {
        const int k0 = kt * 64;
        __syncthreads();   // all waves done reading Ks/Vt of previous tile

        // ---- stage K via global_load_lds (pre-swizzled source) ----
        #pragma unroll
        for (int i = 0; i < 2; ++i) {
            const int row = wid * 16 + i * 8 + (lane >> 3);
            const int ck  = (((lane & 7) ^ (row & 7)) * 8);
            __builtin_amdgcn_global_load_lds(
                (const __attribute__((address_space(1))) void*)(
                    qkv + (baserow + k0 + row) * QR + BDIM + h * HDIM + ck),
                (__attribute__((address_space(3))) void*)(Ks + (wid * 2 + i) * 512),
                16, 0, 0);
        }
        // ---- stage V transposed (reg round-trip, 2B scatter) ----
        #pragma unroll
        for (int i = 0; i < 2; ++i) {
            const int slot = tid + i * 256;
            const int kk = slot >> 3;
            const int c8 = slot & 7;
            const bfrag v8 = *(const bfrag*)(
                qkv + (baserow + k0 + kk) * QR + 2 * BDIM + h * HDIM + c8 * 8);
            #pragma unroll
            for (int j = 0; j < 8; ++j) {
                const int d = c8 * 8 + j;
                Vt[d * 64 + (kk ^ ((d & 7) << 3))] = (unsigned short)v8[j];
            }
        }
        __syncthreads();

        // ---- S = Q K^T ----
        f32x4 s[4] = {};
        #pragma unroll
        for (int ks = 0; ks < 2; ++ks)
            #pragma unroll
            for (int cs = 0; cs < 4; ++cs) {
                const int row = cs * 16 + l15;
                const int ch  = (ks * 4 + l4) ^ (row & 7);
                const bfrag kf = *(const bfrag*)(Ks + row * 64 + ch * 8);
                s[cs] = __builtin_amdgcn_mfma_f32_16x16x32_bf16(qf[ks], kf, s[cs], 0, 0, 0);
            }

        // ---- scale + causal mask ----
        #pragma unroll
        for (int cs = 0; cs < 4; ++cs)
            #pragma unroll
            for (int r = 0; r < 4; ++r)
                s[cs][r] *= 0.125f;
        if (kt == qt) {
            // wave owns q-rows wid*16 .. wid*16+15 of this 64-row tile;
            // D-element r sits at q-row (wid*16 + l4*4 + r), key col cs*16+l15.
            #pragma unroll
            for (int cs = 0; cs < 4; ++cs) {
                const int c = cs * 16 + l15;
                #pragma unroll
                for (int r = 0; r < 4; ++r)
                    if (c > wid * 16 + l4 * 4 + r) s[cs][r] = -3.0e38f;
            }
        }

        // ---- online softmax (rows live at (l4*4+r), cols at l15) ----
        float p[4][4];   // [cs][r]
        #pragma unroll
        for (int r = 0; r < 4; ++r) {
            float mx = fmaxf(fmaxf(s[0][r], s[1][r]), fmaxf(s[2][r], s[3][r]));
            mx = fmaxf(mx, __shfl_xor(mx, 1));
            mx = fmaxf(mx, __shfl_xor(mx, 2));
            mx = fmaxf(mx, __shfl_xor(mx, 4));
            mx = fmaxf(mx, __shfl_xor(mx, 8));
            const float mnew = fmaxf(mrow[r], mx);
            const float fac  = __expf(mrow[r] - mnew);
            mrow[r] = mnew;
            float rsum = 0.f;
            #pragma unroll
            for (int cs = 0; cs < 4; ++cs) {
                p[cs][r] = __expf(s[cs][r] - mnew);
                rsum += p[cs][r];
            }
            rsum += __shfl_xor(rsum, 1);
            rsum += __shfl_xor(rsum, 2);
            rsum += __shfl_xor(rsum, 4);
            rsum += __shfl_xor(rsum, 8);
            lrow[r] = lrow[r] * fac + rsum;
            #pragma unroll
            for (int ds = 0; ds < 4; ++ds) acc_o[ds][r] *= fac;
        }

        // ---- P -> LDS (bf16, swizzled); wave writes & reads only own rows ----
        #pragma unroll
        for (int cs = 0; cs < 4; ++cs)
            #pragma unroll
            for (int r = 0; r < 4; ++r) {
                const int qr = l4 * 4 + r;
                const int c  = cs * 16 + l15;
                Ps[(wid * 16 + qr) * 64 + (c ^ ((qr & 7) << 3))] = f2bf(p[cs][r]);
            }

        // ---- O += P V ----
        #pragma unroll
        for (int ks = 0; ks < 2; ++ks) {
            const int prow = wid * 16 + l15;
            const int pch  = (ks * 4 + l4) ^ (prow & 7);
            const bfrag pf = *(const bfrag*)(Ps + prow * 64 + pch * 8);
            #pragma unroll
            for (int ds = 0; ds < 4; ++ds) {
                const int vrow = ds * 16 + l15;
                const int vch  = (ks * 4 + l4) ^ (vrow & 7);
                const bfrag vf = *(const bfrag*)(Vt + vrow * 64 + vch * 8);
                acc_o[ds] = __builtin_amdgcn_mfma_f32_16x16x32_bf16(pf, vf, acc_o[ds], 0, 0, 0);
            }
        }
    }

    // ---- normalize + store (bf16) ----
    #pragma unroll
    for (int r = 0; r < 4; ++r) {
        const float inv = 1.f / lrow[r];
        unsigned short* orow =
            yatt + (baserow + q0 + wid * 16 + l4 * 4 + r) * BDIM + h * HDIM;
        #pragma unroll
        for (int ds = 0; ds < 4; ++ds)
            orow[ds * 16 + l15] = f2bf(acc_o[ds][r] * inv);
    }
}

// ---------------- launch -----------------------------------------------------
extern "C" void kernel_launch(void* const* d_in, const int* in_sizes, int n_in,
                              void* d_out, int out_size, void* d_ws, size_t ws_size,
                              hipStream_t stream)
{
    const float* x      = (const float*)d_in[0];
    const float* w_qkv  = (const float*)d_in[1];
    const float* b_qkv  = (const float*)d_in[2];
    const float* w_proj = (const float*)d_in[3];
    const float* b_proj = (const float*)d_in[4];
    float* out = (float*)d_out;

    unsigned short* xb   = (unsigned short*)d_ws;                 // [8192][768]
    unsigned short* qkvb = xb   + (size_t)MTOT * BDIM;            // [8192][2304]
    unsigned short* yatt = qkvb + (size_t)MTOT * 3 * BDIM;        // [8192][768]
    unsigned short* wqT  = yatt + (size_t)MTOT * BDIM;            // [2304][768]
    unsigned short* wpT  = wqT  + (size_t)3 * BDIM * BDIM;        // [768][768]

    // prep
    conv_f32_bf16<<<(MTOT * BDIM / 8 + 255) / 256, 256, 0, stream>>>(
        x, xb, MTOT * BDIM / 8);
    transpose_f32_bf16<<<dim3(3 * BDIM / 64, BDIM / 64), 256, 0, stream>>>(
        w_qkv, wqT, BDIM, 3 * BDIM);
    transpose_f32_bf16<<<dim3(BDIM / 64, BDIM / 64), 256, 0, stream>>>(
        w_proj, wpT, BDIM, BDIM);

    // qkv = x @ w_qkv + b_qkv   (bf16 out)
    gemm_mfma_bt<unsigned short><<<dim3(3 * BDIM / 128, MTOT / 128), 256, 0, stream>>>(
        xb, wqT, b_qkv, qkvb, MTOT, 3 * BDIM, BDIM);

    // flash attention
    attn_flash_mfma<<<dim3(SEQ / 64, BATCH * HN), 256, 0, stream>>>(qkvb, yatt);

    // out = yatt @ w_proj + b_proj   (fp32 out)
    gemm_mfma_bt<float><<<dim3(BDIM / 128, MTOT / 128), 256, 0, stream>>>(
        yatt, wpT, b_proj, out, MTOT, BDIM, BDIM);
}

// Round 5
// 181.976 us; speedup vs baseline: 29.1264x; 1.9018x over previous
//
#include <hip/hip_runtime.h>
#include <hip/hip_bf16.h>
#include <cstdint>

#define BDIM 768
#define HN 12
#define HDIM 64
#define SEQ 2048
#define BATCH 4
#define QR (3 * BDIM)          // qkv row stride (elements)
#define MTOT (BATCH * SEQ)     // 8192

typedef __attribute__((ext_vector_type(8))) short bfrag;   // 8 bf16 (4 VGPR)
typedef __attribute__((ext_vector_type(4))) float f32x4;

static __device__ __forceinline__ unsigned short f2bf(float f) {
    union { float f; unsigned u; } v; v.f = f;
    unsigned r = v.u + 0x7FFF + ((v.u >> 16) & 1);   // RNE
    return (unsigned short)(r >> 16);
}

static __device__ __forceinline__ void store_out(float* p, float v) { *p = v; }
static __device__ __forceinline__ void store_out(unsigned short* p, float v) { *p = f2bf(v); }

// ---------------- prep: fp32 -> bf16 flat convert ---------------------------
__global__ __launch_bounds__(256) void conv_f32_bf16(
    const float* __restrict__ in, unsigned short* __restrict__ out, int n8)
{
    const int i = blockIdx.x * 256 + threadIdx.x;
    if (i >= n8) return;
    const float4 a = ((const float4*)in)[i * 2];
    const float4 b = ((const float4*)in)[i * 2 + 1];
    bfrag o;
    o[0] = f2bf(a.x); o[1] = f2bf(a.y); o[2] = f2bf(a.z); o[3] = f2bf(a.w);
    o[4] = f2bf(b.x); o[5] = f2bf(b.y); o[6] = f2bf(b.z); o[7] = f2bf(b.w);
    ((bfrag*)out)[i] = o;
}

// ---------------- prep: [R][C] fp32 -> [C][R] bf16 transpose ----------------
__global__ __launch_bounds__(256) void transpose_f32_bf16(
    const float* __restrict__ in, unsigned short* __restrict__ out, int R, int C)
{
    __shared__ unsigned short t[64][72];
    const int tid = threadIdx.x;
    const int c0 = blockIdx.x * 64, r0 = blockIdx.y * 64;
    #pragma unroll
    for (int i = 0; i < 4; ++i) {
        const int r = (tid >> 4) + i * 16;
        const int c = (tid & 15) * 4;
        const float4 v = *(const float4*)&in[(size_t)(r0 + r) * C + c0 + c];
        t[c + 0][r] = f2bf(v.x);
        t[c + 1][r] = f2bf(v.y);
        t[c + 2][r] = f2bf(v.z);
        t[c + 3][r] = f2bf(v.w);
    }
    __syncthreads();
    #pragma unroll
    for (int i = 0; i < 2; ++i) {
        const int c = (tid >> 3) + i * 32;
        const int r = (tid & 7) * 8;
        *(bfrag*)&out[(size_t)(c0 + c) * R + r0 + r] = *(const bfrag*)&t[c][r];
    }
}

// ---------------- prep: V part of qkv -> vT[bh*64 + d][s] (bf16) ------------
__global__ __launch_bounds__(256) void transpose_v(
    const unsigned short* __restrict__ qkvb, unsigned short* __restrict__ vT)
{
    __shared__ unsigned short t[64][76];
    const int bh = blockIdx.y, h = bh % HN, b = bh / HN;
    const int s0 = blockIdx.x * 64;
    const int tid = threadIdx.x;
    #pragma unroll
    for (int it = 0; it < 2; ++it) {
        const int slot = it * 256 + tid;
        const int r = slot >> 3, c8 = slot & 7;
        const bfrag v = *(const bfrag*)(
            qkvb + ((size_t)(b * SEQ + s0 + r)) * QR + 2 * BDIM + h * HDIM + c8 * 8);
        #pragma unroll
        for (int j = 0; j < 8; ++j) t[c8 * 8 + j][r] = (unsigned short)v[j];
    }
    __syncthreads();
    #pragma unroll
    for (int it = 0; it < 2; ++it) {
        const int slot = it * 256 + tid;
        const int d = slot >> 3, s8 = slot & 7;
        bfrag o;
        #pragma unroll
        for (int j = 0; j < 8; ++j) o[j] = (short)t[d][s8 * 8 + j];
        *(bfrag*)(vT + ((size_t)bh * HDIM + d) * SEQ + s0 + s8 * 8) = o;
    }
}

// ---------------- bf16 MFMA GEMM: C[M,N] = A[M,K] @ Bt[N,K]^T + bias --------
template <typename OUTT>
__global__ __launch_bounds__(256) void gemm_mfma_bt(
    const unsigned short* __restrict__ A,   // [M][K] bf16
    const unsigned short* __restrict__ Bt,  // [N][K] bf16
    const float* __restrict__ bias,
    OUTT* __restrict__ C, int M, int N, int K)
{
    __shared__ unsigned short As[128 * 64];
    __shared__ unsigned short Bs[128 * 64];

    const int tid  = threadIdx.x;
    const int lane = tid & 63;
    const int wid  = tid >> 6;
    const int l15  = lane & 15;
    const int l4   = lane >> 4;
    const int m0 = blockIdx.y * 128;
    const int n0 = blockIdx.x * 128;
    const int wm = (wid >> 1) * 64;
    const int wn = (wid & 1) * 64;

    f32x4 acc[4][4] = {};

    for (int k0 = 0; k0 < K; k0 += 64) {
        __syncthreads();
        #pragma unroll
        for (int i = 0; i < 4; ++i) {
            const int row = wid * 32 + i * 8 + (lane >> 3);
            const int ck  = (((lane & 7) ^ (row & 7)) * 8);
            __builtin_amdgcn_global_load_lds(
                (const __attribute__((address_space(1))) void*)(A + (size_t)(m0 + row) * K + k0 + ck),
                (__attribute__((address_space(3))) void*)(As + (wid * 4 + i) * 512),
                16, 0, 0);
            __builtin_amdgcn_global_load_lds(
                (const __attribute__((address_space(1))) void*)(Bt + (size_t)(n0 + row) * K + k0 + ck),
                (__attribute__((address_space(3))) void*)(Bs + (wid * 4 + i) * 512),
                16, 0, 0);
        }
        __syncthreads();

        #pragma unroll
        for (int ks = 0; ks < 2; ++ks) {
            bfrag af[4], bfv[4];
            #pragma unroll
            for (int mi = 0; mi < 4; ++mi) {
                const int row = wm + mi * 16 + l15;
                const int ch  = (ks * 4 + l4) ^ (row & 7);
                af[mi] = *(const bfrag*)(As + row * 64 + ch * 8);
            }
            #pragma unroll
            for (int ni = 0; ni < 4; ++ni) {
                const int row = wn + ni * 16 + l15;
                const int ch  = (ks * 4 + l4) ^ (row & 7);
                bfv[ni] = *(const bfrag*)(Bs + row * 64 + ch * 8);
            }
            #pragma unroll
            for (int mi = 0; mi < 4; ++mi)
                #pragma unroll
                for (int ni = 0; ni < 4; ++ni)
                    acc[mi][ni] = __builtin_amdgcn_mfma_f32_16x16x32_bf16(
                        af[mi], bfv[ni], acc[mi][ni], 0, 0, 0);
        }
    }

    #pragma unroll
    for (int mi = 0; mi < 4; ++mi)
        #pragma unroll
        for (int ni = 0; ni < 4; ++ni) {
            const int n = n0 + wn + ni * 16 + l15;
            const float bv = bias[n];
            #pragma unroll
            for (int r = 0; r < 4; ++r) {
                const int m = m0 + wm + mi * 16 + l4 * 4 + r;
                store_out(C + (size_t)m * N + n, acc[mi][ni][r] + bv);
            }
        }
}

// ---------------- MFMA flash attention (paired tiles + dbuf) -----------------
// qkv bf16 [B*S][2304] (Q,K); vT bf16 [48*64][2048]; yatt bf16 [B*S][768].
// 768 uniform blocks: block -> (bh, pair); handles q-tiles {pair, 31-pair}.
__global__ __launch_bounds__(256, 4) void attn_flash_mfma(
    const unsigned short* __restrict__ qkv,
    const unsigned short* __restrict__ vT,
    unsigned short* __restrict__ yatt)
{
    __shared__ unsigned short Ks[2][64 * 64];   // [k][d] swizzled
    __shared__ unsigned short Vs[2][64 * 64];   // [d][k] swizzled
    __shared__ unsigned short Ps[64 * 64];      // [q][k] swizzled (wave-private rows)

    const int bid  = blockIdx.x;
    const int lid  = (bid & 7) * 96 + (bid >> 3);   // XCD-grouped remap (768 = 8*96)
    const int pair = lid & 15;
    const int bh   = lid >> 4;
    const int h = bh % HN, b = bh / HN;

    const int tid  = threadIdx.x;
    const int lane = tid & 63;
    const int wid  = tid >> 6;
    const int l15  = lane & 15;
    const int l4   = lane >> 4;

    const size_t baserow = (size_t)b * SEQ;
    const unsigned short* kg = qkv + baserow * QR + BDIM + h * HDIM;  // + k*QR
    const unsigned short* vg = vT + (size_t)bh * HDIM * SEQ;          // + d*SEQ

    auto stage = [&](int bufi, int kt) {
        const int k0 = kt * 64;
        #pragma unroll
        for (int i = 0; i < 2; ++i) {
            const int row = wid * 16 + i * 8 + (lane >> 3);
            const int ck  = (((lane & 7) ^ (row & 7)) * 8);
            __builtin_amdgcn_global_load_lds(
                (const __attribute__((address_space(1))) void*)(kg + (size_t)(k0 + row) * QR + ck),
                (__attribute__((address_space(3))) void*)(&Ks[bufi][(wid * 16 + i * 8) * 64]),
                16, 0, 0);
            __builtin_amdgcn_global_load_lds(
                (const __attribute__((address_space(1))) void*)(vg + (size_t)row * SEQ + k0 + ck),
                (__attribute__((address_space(3))) void*)(&Vs[bufi][(wid * 16 + i * 8) * 64]),
                16, 0, 0);
        }
    };

    #pragma unroll 1
    for (int seg = 0; seg < 2; ++seg) {
        const int qt = seg ? (31 - pair) : pair;
        const int q0 = qt * 64;

        // Q fragments in registers
        const unsigned short* qrow =
            qkv + (baserow + q0 + wid * 16 + l15) * QR + h * HDIM;
        const bfrag qf0 = *(const bfrag*)(qrow + l4 * 8);
        const bfrag qf1 = *(const bfrag*)(qrow + 32 + l4 * 8);

        f32x4 acc_o[4] = {};
        float mrow[4] = {-3.0e38f, -3.0e38f, -3.0e38f, -3.0e38f};
        float lrow[4] = {};

        __syncthreads();         // protect buffers from previous segment
        stage(0, 0);
        __syncthreads();

        int buf = 0;
        for (int kt = 0;;) {
            if (kt < qt) stage(buf ^ 1, kt + 1);   // async prefetch next tile

            const unsigned short* Kb = Ks[buf];
            const unsigned short* Vb = Vs[buf];

            // ---- S = Q K^T ----
            f32x4 s[4] = {};
            __builtin_amdgcn_s_setprio(1);
            #pragma unroll
            for (int ks = 0; ks < 2; ++ks) {
                const bfrag qk = ks ? qf1 : qf0;
                #pragma unroll
                for (int cs = 0; cs < 4; ++cs) {
                    const int row = cs * 16 + l15;
                    const int ch  = (ks * 4 + l4) ^ (row & 7);
                    const bfrag kf = *(const bfrag*)(Kb + row * 64 + ch * 8);
                    s[cs] = __builtin_amdgcn_mfma_f32_16x16x32_bf16(qk, kf, s[cs], 0, 0, 0);
                }
            }
            __builtin_amdgcn_s_setprio(0);

            // ---- scale + causal mask ----
            #pragma unroll
            for (int cs = 0; cs < 4; ++cs)
                #pragma unroll
                for (int r = 0; r < 4; ++r)
                    s[cs][r] *= 0.125f;
            if (kt == qt) {
                #pragma unroll
                for (int cs = 0; cs < 4; ++cs) {
                    const int c = cs * 16 + l15;
                    #pragma unroll
                    for (int r = 0; r < 4; ++r)
                        if (c > wid * 16 + l4 * 4 + r) s[cs][r] = -3.0e38f;
                }
            }

            // ---- online softmax ----
            float p[4][4];
            #pragma unroll
            for (int r = 0; r < 4; ++r) {
                float mx = fmaxf(fmaxf(s[0][r], s[1][r]), fmaxf(s[2][r], s[3][r]));
                mx = fmaxf(mx, __shfl_xor(mx, 1));
                mx = fmaxf(mx, __shfl_xor(mx, 2));
                mx = fmaxf(mx, __shfl_xor(mx, 4));
                mx = fmaxf(mx, __shfl_xor(mx, 8));
                const float mnew = fmaxf(mrow[r], mx);
                const float fac  = __expf(mrow[r] - mnew);
                mrow[r] = mnew;
                float rsum = 0.f;
                #pragma unroll
                for (int cs = 0; cs < 4; ++cs) {
                    p[cs][r] = __expf(s[cs][r] - mnew);
                    rsum += p[cs][r];
                }
                rsum += __shfl_xor(rsum, 1);
                rsum += __shfl_xor(rsum, 2);
                rsum += __shfl_xor(rsum, 4);
                rsum += __shfl_xor(rsum, 8);
                lrow[r] = lrow[r] * fac + rsum;
                #pragma unroll
                for (int ds = 0; ds < 4; ++ds) acc_o[ds][r] *= fac;
            }

            // ---- P -> LDS (wave-private rows, swizzled) ----
            #pragma unroll
            for (int cs = 0; cs < 4; ++cs)
                #pragma unroll
                for (int r = 0; r < 4; ++r) {
                    const int qr = l4 * 4 + r;
                    const int c  = cs * 16 + l15;
                    Ps[(wid * 16 + qr) * 64 + (c ^ ((qr & 7) << 3))] = f2bf(p[cs][r]);
                }

            // ---- O += P V ----
            __builtin_amdgcn_s_setprio(1);
            #pragma unroll
            for (int ks = 0; ks < 2; ++ks) {
                const int prow = wid * 16 + l15;
                const int pch  = (ks * 4 + l4) ^ (prow & 7);
                const bfrag pf = *(const bfrag*)(Ps + prow * 64 + pch * 8);
                #pragma unroll
                for (int ds = 0; ds < 4; ++ds) {
                    const int vrow = ds * 16 + l15;
                    const int vch  = (ks * 4 + l4) ^ (vrow & 7);
                    const bfrag vf = *(const bfrag*)(Vb + vrow * 64 + vch * 8);
                    acc_o[ds] = __builtin_amdgcn_mfma_f32_16x16x32_bf16(pf, vf, acc_o[ds], 0, 0, 0);
                }
            }
            __builtin_amdgcn_s_setprio(0);

            if (kt == qt) break;
            __syncthreads();      // drains own gload_lds (vmcnt) + all waves done
            buf ^= 1; ++kt;
        }

        // ---- normalize + store (bf16) ----
        #pragma unroll
        for (int r = 0; r < 4; ++r) {
            const float inv = 1.f / lrow[r];
            unsigned short* orow =
                yatt + (baserow + q0 + wid * 16 + l4 * 4 + r) * BDIM + h * HDIM;
            #pragma unroll
            for (int ds = 0; ds < 4; ++ds)
                orow[ds * 16 + l15] = f2bf(acc_o[ds][r] * inv);
        }
    }
}

// ---------------- launch -----------------------------------------------------
extern "C" void kernel_launch(void* const* d_in, const int* in_sizes, int n_in,
                              void* d_out, int out_size, void* d_ws, size_t ws_size,
                              hipStream_t stream)
{
    const float* x      = (const float*)d_in[0];
    const float* w_qkv  = (const float*)d_in[1];
    const float* b_qkv  = (const float*)d_in[2];
    const float* w_proj = (const float*)d_in[3];
    const float* b_proj = (const float*)d_in[4];
    float* out = (float*)d_out;

    unsigned short* xb   = (unsigned short*)d_ws;                 // [8192][768]
    unsigned short* qkvb = xb   + (size_t)MTOT * BDIM;            // [8192][2304]
    unsigned short* yatt = qkvb + (size_t)MTOT * 3 * BDIM;        // [8192][768]
    unsigned short* wqT  = yatt + (size_t)MTOT * BDIM;            // [2304][768]
    unsigned short* wpT  = wqT  + (size_t)3 * BDIM * BDIM;        // [768][768]
    unsigned short* vT   = xb;   // reuse: xb dead after GEMM1    // [48*64][2048]

    // prep
    conv_f32_bf16<<<(MTOT * BDIM / 8 + 255) / 256, 256, 0, stream>>>(
        x, xb, MTOT * BDIM / 8);
    transpose_f32_bf16<<<dim3(3 * BDIM / 64, BDIM / 64), 256, 0, stream>>>(
        w_qkv, wqT, BDIM, 3 * BDIM);
    transpose_f32_bf16<<<dim3(BDIM / 64, BDIM / 64), 256, 0, stream>>>(
        w_proj, wpT, BDIM, BDIM);

    // qkv = x @ w_qkv + b_qkv   (bf16 out)
    gemm_mfma_bt<unsigned short><<<dim3(3 * BDIM / 128, MTOT / 128), 256, 0, stream>>>(
        xb, wqT, b_qkv, qkvb, MTOT, 3 * BDIM, BDIM);

    // V -> vT (overwrites xb)
    transpose_v<<<dim3(SEQ / 64, BATCH * HN), 256, 0, stream>>>(qkvb, vT);

    // flash attention (uniform-work pairing)
    attn_flash_mfma<<<dim3(768), 256, 0, stream>>>(qkvb, vT, yatt);

    // out = yatt @ w_proj + b_proj   (fp32 out)
    gemm_mfma_bt<float><<<dim3(BDIM / 128, MTOT / 128), 256, 0, stream>>>(
        yatt, wpT, b_proj, out, MTOT, BDIM, BDIM);
}

// Round 6
// 170.582 us; speedup vs baseline: 31.0719x; 1.0668x over previous
//
#include <hip/hip_runtime.h>
#include <hip/hip_bf16.h>
#include <cstdint>

#define BDIM 768
#define HN 12
#define HDIM 64
#define SEQ 2048
#define BATCH 4
#define QR (3 * BDIM)          // qkv row stride (elements)
#define MTOT (BATCH * SEQ)     // 8192

typedef __attribute__((ext_vector_type(8))) short bfrag;   // 8 bf16 (4 VGPR)
typedef __attribute__((ext_vector_type(4))) float f32x4;

static __device__ __forceinline__ unsigned short f2bf(float f) {
    union { float f; unsigned u; } v; v.f = f;
    unsigned r = v.u + 0x7FFF + ((v.u >> 16) & 1);   // RNE
    return (unsigned short)(r >> 16);
}

static __device__ __forceinline__ float fexp2(float x) {
    float r; asm("v_exp_f32 %0, %1" : "=v"(r) : "v"(x)); return r;
}

static __device__ __forceinline__ unsigned cvt_pk_bf16(float lo, float hi) {
    unsigned r;
    asm("v_cvt_pk_bf16_f32 %0, %1, %2" : "=v"(r) : "v"(lo), "v"(hi));
    return r;
}

static __device__ __forceinline__ void store_out(float* p, float v) { *p = v; }
static __device__ __forceinline__ void store_out(unsigned short* p, float v) { *p = f2bf(v); }

// ---------------- prep: fp32 -> bf16 flat convert ---------------------------
__global__ __launch_bounds__(256) void conv_f32_bf16(
    const float* __restrict__ in, unsigned short* __restrict__ out, int n8)
{
    const int i = blockIdx.x * 256 + threadIdx.x;
    if (i >= n8) return;
    const float4 a = ((const float4*)in)[i * 2];
    const float4 b = ((const float4*)in)[i * 2 + 1];
    bfrag o;
    o[0] = f2bf(a.x); o[1] = f2bf(a.y); o[2] = f2bf(a.z); o[3] = f2bf(a.w);
    o[4] = f2bf(b.x); o[5] = f2bf(b.y); o[6] = f2bf(b.z); o[7] = f2bf(b.w);
    ((bfrag*)out)[i] = o;
}

// ---------------- prep: [R][C] fp32 -> [C][R] bf16 transpose ----------------
__global__ __launch_bounds__(256) void transpose_f32_bf16(
    const float* __restrict__ in, unsigned short* __restrict__ out, int R, int C)
{
    __shared__ unsigned short t[64][72];
    const int tid = threadIdx.x;
    const int c0 = blockIdx.x * 64, r0 = blockIdx.y * 64;
    #pragma unroll
    for (int i = 0; i < 4; ++i) {
        const int r = (tid >> 4) + i * 16;
        const int c = (tid & 15) * 4;
        const float4 v = *(const float4*)&in[(size_t)(r0 + r) * C + c0 + c];
        t[c + 0][r] = f2bf(v.x);
        t[c + 1][r] = f2bf(v.y);
        t[c + 2][r] = f2bf(v.z);
        t[c + 3][r] = f2bf(v.w);
    }
    __syncthreads();
    #pragma unroll
    for (int i = 0; i < 2; ++i) {
        const int c = (tid >> 3) + i * 32;
        const int r = (tid & 7) * 8;
        *(bfrag*)&out[(size_t)(c0 + c) * R + r0 + r] = *(const bfrag*)&t[c][r];
    }
}

// ---------------- prep: V part of qkv -> vT[bh*64 + d][s]; zero queue -------
__global__ __launch_bounds__(256) void transpose_v(
    const unsigned short* __restrict__ qkvb, unsigned short* __restrict__ vT,
    int* __restrict__ qctr)
{
    if (blockIdx.x == 0 && blockIdx.y == 0 && threadIdx.x < 8)
        qctr[threadIdx.x] = 0;
    __shared__ unsigned short t[64][76];
    const int bh = blockIdx.y, h = bh % HN, b = bh / HN;
    const int s0 = blockIdx.x * 64;
    const int tid = threadIdx.x;
    #pragma unroll
    for (int it = 0; it < 2; ++it) {
        const int slot = it * 256 + tid;
        const int r = slot >> 3, c8 = slot & 7;
        const bfrag v = *(const bfrag*)(
            qkvb + ((size_t)(b * SEQ + s0 + r)) * QR + 2 * BDIM + h * HDIM + c8 * 8);
        #pragma unroll
        for (int j = 0; j < 8; ++j) t[c8 * 8 + j][r] = (unsigned short)v[j];
    }
    __syncthreads();
    #pragma unroll
    for (int it = 0; it < 2; ++it) {
        const int slot = it * 256 + tid;
        const int d = slot >> 3, s8 = slot & 7;
        bfrag o;
        #pragma unroll
        for (int j = 0; j < 8; ++j) o[j] = (short)t[d][s8 * 8 + j];
        *(bfrag*)(vT + ((size_t)bh * HDIM + d) * SEQ + s0 + s8 * 8) = o;
    }
}

// ---------------- bf16 MFMA GEMM: C[M,N] = A[M,K] @ Bt[N,K]^T + bias --------
template <typename OUTT>
__global__ __launch_bounds__(256) void gemm_mfma_bt(
    const unsigned short* __restrict__ A,   // [M][K] bf16
    const unsigned short* __restrict__ Bt,  // [N][K] bf16
    const float* __restrict__ bias,
    OUTT* __restrict__ C, int M, int N, int K)
{
    __shared__ unsigned short As[128 * 64];
    __shared__ unsigned short Bs[128 * 64];

    const int tid  = threadIdx.x;
    const int lane = tid & 63;
    const int wid  = tid >> 6;
    const int l15  = lane & 15;
    const int l4   = lane >> 4;
    const int m0 = blockIdx.y * 128;
    const int n0 = blockIdx.x * 128;
    const int wm = (wid >> 1) * 64;
    const int wn = (wid & 1) * 64;

    f32x4 acc[4][4] = {};

    for (int k0 = 0; k0 < K; k0 += 64) {
        __syncthreads();
        #pragma unroll
        for (int i = 0; i < 4; ++i) {
            const int row = wid * 32 + i * 8 + (lane >> 3);
            const int ck  = (((lane & 7) ^ (row & 7)) * 8);
            __builtin_amdgcn_global_load_lds(
                (const __attribute__((address_space(1))) void*)(A + (size_t)(m0 + row) * K + k0 + ck),
                (__attribute__((address_space(3))) void*)(As + (wid * 4 + i) * 512),
                16, 0, 0);
            __builtin_amdgcn_global_load_lds(
                (const __attribute__((address_space(1))) void*)(Bt + (size_t)(n0 + row) * K + k0 + ck),
                (__attribute__((address_space(3))) void*)(Bs + (wid * 4 + i) * 512),
                16, 0, 0);
        }
        __syncthreads();

        #pragma unroll
        for (int ks = 0; ks < 2; ++ks) {
            bfrag af[4], bfv[4];
            #pragma unroll
            for (int mi = 0; mi < 4; ++mi) {
                const int row = wm + mi * 16 + l15;
                const int ch  = (ks * 4 + l4) ^ (row & 7);
                af[mi] = *(const bfrag*)(As + row * 64 + ch * 8);
            }
            #pragma unroll
            for (int ni = 0; ni < 4; ++ni) {
                const int row = wn + ni * 16 + l15;
                const int ch  = (ks * 4 + l4) ^ (row & 7);
                bfv[ni] = *(const bfrag*)(Bs + row * 64 + ch * 8);
            }
            #pragma unroll
            for (int mi = 0; mi < 4; ++mi)
                #pragma unroll
                for (int ni = 0; ni < 4; ++ni)
                    acc[mi][ni] = __builtin_amdgcn_mfma_f32_16x16x32_bf16(
                        af[mi], bfv[ni], acc[mi][ni], 0, 0, 0);
        }
    }

    #pragma unroll
    for (int mi = 0; mi < 4; ++mi)
        #pragma unroll
        for (int ni = 0; ni < 4; ++ni) {
            const int n = n0 + wn + ni * 16 + l15;
            const float bv = bias[n];
            #pragma unroll
            for (int r = 0; r < 4; ++r) {
                const int m = m0 + wm + mi * 16 + l4 * 4 + r;
                store_out(C + (size_t)m * N + n, acc[mi][ni][r] + bv);
            }
        }
}

// ---------------- MFMA flash attention (swapped QK^T, in-reg softmax) -------
// Work queue: 8 per-"XCD" queues of 192 items (6 heads x 32 q-tiles,
// longest-first). Block = 4 waves; wave owns 16 q-rows; KVBLK=64, dbuf LDS.
#define C2 0.18033688011112042f   /* 0.125 * log2(e) */
#define THR 8.0f

__global__ __launch_bounds__(256, 5) void attn_flash_mfma(
    const unsigned short* __restrict__ qkv,
    const unsigned short* __restrict__ vT,
    unsigned short* __restrict__ yatt,
    int* __restrict__ qctr)
{
    __shared__ unsigned short Ks[2][64 * 64];   // [k][d] swizzled
    __shared__ unsigned short Vs[2][64 * 64];   // [d][k] swizzled

    const int hint = blockIdx.x & 7;
    const int tid  = threadIdx.x;
    const int lane = tid & 63;
    const int wid  = tid >> 6;
    const int l15  = lane & 15;
    const int l4   = lane >> 4;

    for (;;) {
        __syncthreads();                       // prev item's compute done
        if (tid == 0) *(int*)Ks = atomicAdd(&qctr[hint], 1);
        __syncthreads();
        const int it = *(const int*)Ks;
        if (it >= 192) break;
        __syncthreads();                       // all read `it` before staging
        const int bh = hint * 6 + (it % 6);
        const int qt = 31 - (it / 6);
        const int h = bh % HN, b = bh / HN;
        const int q0 = qt * 64;

        const size_t baserow = (size_t)b * SEQ;
        const unsigned short* kg = qkv + baserow * QR + BDIM + h * HDIM;
        const unsigned short* vg = vT + (size_t)bh * HDIM * SEQ;

        // Q fragments (B-operand): Q[q = q0+wid*16+l15][d = ks*32 + l4*8 + j]
        const unsigned short* qrow =
            qkv + (baserow + q0 + wid * 16 + l15) * QR + h * HDIM;
        const bfrag qf0 = *(const bfrag*)(qrow + l4 * 8);
        const bfrag qf1 = *(const bfrag*)(qrow + 32 + l4 * 8);

        f32x4 acc_o[4] = {};
        float m = -3.0e38f;
        float l = 0.f;

        // prologue stage tile 0
        #pragma unroll
        for (int i = 0; i < 2; ++i) {
            const int row = wid * 16 + i * 8 + (lane >> 3);
            const int ck  = (((lane & 7) ^ (row & 7)) * 8);
            __builtin_amdgcn_global_load_lds(
                (const __attribute__((address_space(1))) void*)(kg + (size_t)row * QR + ck),
                (__attribute__((address_space(3))) void*)(&Ks[0][row * 64]),
                16, 0, 0);
            __builtin_amdgcn_global_load_lds(
                (const __attribute__((address_space(1))) void*)(vg + (size_t)row * SEQ + ck),
                (__attribute__((address_space(3))) void*)(&Vs[0][row * 64]),
                16, 0, 0);
        }
        __syncthreads();

        int buf = 0;
        for (int kt = 0;;) {
            if (kt < qt) {                    // async prefetch next tile
                const int k0n = (kt + 1) * 64;
                #pragma unroll
                for (int i = 0; i < 2; ++i) {
                    const int row = wid * 16 + i * 8 + (lane >> 3);
                    const int ck  = (((lane & 7) ^ (row & 7)) * 8);
                    __builtin_amdgcn_global_load_lds(
                        (const __attribute__((address_space(1))) void*)(kg + (size_t)(k0n + row) * QR + ck),
                        (__attribute__((address_space(3))) void*)(&Ks[buf ^ 1][row * 64]),
                        16, 0, 0);
                    __builtin_amdgcn_global_load_lds(
                        (const __attribute__((address_space(1))) void*)(vg + (size_t)row * SEQ + k0n + ck),
                        (__attribute__((address_space(3))) void*)(&Vs[buf ^ 1][row * 64]),
                        16, 0, 0);
                }
            }

            const unsigned short* Kb = Ks[buf];
            const unsigned short* Vb = Vs[buf];

            // ---- S^T = K Q^T : lane holds S[k = cs*16+l4*4+r][q = l15] ----
            f32x4 s[4] = {};
            __builtin_amdgcn_s_setprio(1);
            #pragma unroll
            for (int ks = 0; ks < 2; ++ks) {
                const bfrag qk = ks ? qf1 : qf0;
                #pragma unroll
                for (int cs = 0; cs < 4; ++cs) {
                    const int row = cs * 16 + l15;
                    const int ch  = (ks * 4 + l4) ^ (row & 7);
                    const bfrag kf = *(const bfrag*)(Kb + row * 64 + ch * 8);
                    s[cs] = __builtin_amdgcn_mfma_f32_16x16x32_bf16(kf, qk, s[cs], 0, 0, 0);
                }
            }
            __builtin_amdgcn_s_setprio(0);

            // ---- causal mask on diagonal tile (k > q) ----
            if (kt == qt) {
                #pragma unroll
                for (int cs = 0; cs < 4; ++cs)
                    #pragma unroll
                    for (int r = 0; r < 4; ++r)
                        if (cs * 16 + l4 * 4 + r > wid * 16 + l15)
                            s[cs][r] = -3.0e38f;
            }

            // ---- lane-local online softmax (row q=l15; k spread over l4) ----
            float mx = s[0][0];
            #pragma unroll
            for (int cs = 0; cs < 4; ++cs)
                #pragma unroll
                for (int r = 0; r < 4; ++r) mx = fmaxf(mx, s[cs][r]);
            mx = fmaxf(mx, __shfl_xor(mx, 16));
            mx = fmaxf(mx, __shfl_xor(mx, 32));
            const float mx2 = mx * C2;

            if (!__all(mx2 <= m + THR)) {     // rescale path
                const float mnew = fmaxf(m, mx2);
                const float fac  = fexp2(m - mnew);
                m = mnew;
                l *= fac;
                #pragma unroll
                for (int r = 0; r < 4; ++r) {
                    const float fr = __shfl(fac, (lane & 48) | (l4 * 4 + r));
                    #pragma unroll
                    for (int ds = 0; ds < 4; ++ds) acc_o[ds][r] *= fr;
                }
            }

            float rsum = 0.f;
            #pragma unroll
            for (int cs = 0; cs < 4; ++cs)
                #pragma unroll
                for (int r = 0; r < 4; ++r) {
                    const float pv = fexp2(fmaf(s[cs][r], C2, -m));
                    s[cs][r] = pv;
                    rsum += pv;
                }
            rsum += __shfl_xor(rsum, 16);
            rsum += __shfl_xor(rsum, 32);
            l += rsum;

            // ---- P -> bf16 pairs, redistribute to PV A-fragment in-reg ----
            unsigned pk[4][2];
            #pragma unroll
            for (int cs = 0; cs < 4; ++cs) {
                pk[cs][0] = cvt_pk_bf16(s[cs][0], s[cs][1]);
                pk[cs][1] = cvt_pk_bf16(s[cs][2], s[cs][3]);
            }
            union { bfrag f; unsigned u[4]; } pf[2];
            #pragma unroll
            for (int ks = 0; ks < 2; ++ks)
                #pragma unroll
                for (int i = 0; i < 2; ++i) {
                    const unsigned A  = pk[ks * 2][i];
                    const unsigned B  = pk[ks * 2 + 1][i];
                    const unsigned Ax = __shfl_xor(A, 32);
                    const unsigned Bx = __shfl_xor(B, 32);
                    const unsigned P1 = (l4 < 2) ? A : Bx;
                    const unsigned P2 = (l4 < 2) ? Ax : B;
                    const unsigned S1 = __shfl_xor(P1, 16);
                    const unsigned S2 = __shfl_xor(P2, 16);
                    pf[ks].u[i]     = (l4 & 1) ? S2 : P1;
                    pf[ks].u[2 + i] = (l4 & 1) ? P2 : S1;
                }

            // ---- O += P V ----
            __builtin_amdgcn_s_setprio(1);
            #pragma unroll
            for (int ks = 0; ks < 2; ++ks)
                #pragma unroll
                for (int ds = 0; ds < 4; ++ds) {
                    const int vrow = ds * 16 + l15;
                    const int vch  = (ks * 4 + l4) ^ (vrow & 7);
                    const bfrag vf = *(const bfrag*)(Vb + vrow * 64 + vch * 8);
                    acc_o[ds] = __builtin_amdgcn_mfma_f32_16x16x32_bf16(pf[ks].f, vf, acc_o[ds], 0, 0, 0);
                }
            __builtin_amdgcn_s_setprio(0);

            if (kt == qt) break;
            __syncthreads();      // drains own gload_lds + all waves done
            buf ^= 1; ++kt;
        }

        // ---- normalize + store (bf16); l lives at lane with l15 == q ----
        const float inv = 1.f / l;
        #pragma unroll
        for (int r = 0; r < 4; ++r) {
            const float invr = __shfl(inv, (lane & 48) | (l4 * 4 + r));
            unsigned short* orow =
                yatt + (baserow + q0 + wid * 16 + l4 * 4 + r) * BDIM + h * HDIM;
            #pragma unroll
            for (int ds = 0; ds < 4; ++ds)
                orow[ds * 16 + l15] = f2bf(acc_o[ds][r] * invr);
        }
    }
}

// ---------------- launch -----------------------------------------------------
extern "C" void kernel_launch(void* const* d_in, const int* in_sizes, int n_in,
                              void* d_out, int out_size, void* d_ws, size_t ws_size,
                              hipStream_t stream)
{
    const float* x      = (const float*)d_in[0];
    const float* w_qkv  = (const float*)d_in[1];
    const float* b_qkv  = (const float*)d_in[2];
    const float* w_proj = (const float*)d_in[3];
    const float* b_proj = (const float*)d_in[4];
    float* out = (float*)d_out;

    unsigned short* xb   = (unsigned short*)d_ws;                 // [8192][768]
    unsigned short* qkvb = xb   + (size_t)MTOT * BDIM;            // [8192][2304]
    unsigned short* yatt = qkvb + (size_t)MTOT * 3 * BDIM;        // [8192][768]
    unsigned short* wqT  = yatt + (size_t)MTOT * BDIM;            // [2304][768]
    unsigned short* wpT  = wqT  + (size_t)3 * BDIM * BDIM;        // [768][768]
    int*            qctr = (int*)(wpT + (size_t)BDIM * BDIM);     // [8]
    unsigned short* vT   = xb;   // reuse: xb dead after GEMM1    // [48*64][2048]

    // prep
    conv_f32_bf16<<<(MTOT * BDIM / 8 + 255) / 256, 256, 0, stream>>>(
        x, xb, MTOT * BDIM / 8);
    transpose_f32_bf16<<<dim3(3 * BDIM / 64, BDIM / 64), 256, 0, stream>>>(
        w_qkv, wqT, BDIM, 3 * BDIM);
    transpose_f32_bf16<<<dim3(BDIM / 64, BDIM / 64), 256, 0, stream>>>(
        w_proj, wpT, BDIM, BDIM);

    // qkv = x @ w_qkv + b_qkv   (bf16 out)
    gemm_mfma_bt<unsigned short><<<dim3(3 * BDIM / 128, MTOT / 128), 256, 0, stream>>>(
        xb, wqT, b_qkv, qkvb, MTOT, 3 * BDIM, BDIM);

    // V -> vT (overwrites xb) + zero the work queues
    transpose_v<<<dim3(SEQ / 64, BATCH * HN), 256, 0, stream>>>(qkvb, vT, qctr);

    // flash attention (work-stealing queues, 5 blocks/CU)
    attn_flash_mfma<<<dim3(1280), 256, 0, stream>>>(qkvb, vT, yatt, qctr);

    // out = yatt @ w_proj + b_proj   (fp32 out)
    gemm_mfma_bt<float><<<dim3(BDIM / 128, MTOT / 128), 256, 0, stream>>>(
        yatt, wpT, b_proj, out, MTOT, BDIM, BDIM);
}

// Round 7
// 165.687 us; speedup vs baseline: 31.9899x; 1.0295x over previous
//
#include <hip/hip_runtime.h>
#include <hip/hip_bf16.h>
#include <cstdint>

#define BDIM 768
#define HN 12
#define HDIM 64
#define SEQ 2048
#define BATCH 4
#define QR (3 * BDIM)          // qkv row stride (elements)
#define MTOT (BATCH * SEQ)     // 8192

typedef __attribute__((ext_vector_type(8))) short bfrag;   // 8 bf16 (4 VGPR)
typedef __attribute__((ext_vector_type(4))) float f32x4;

static __device__ __forceinline__ unsigned short f2bf(float f) {
    union { float f; unsigned u; } v; v.f = f;
    unsigned r = v.u + 0x7FFF + ((v.u >> 16) & 1);   // RNE
    return (unsigned short)(r >> 16);
}

static __device__ __forceinline__ float fexp2(float x) {
    float r; asm("v_exp_f32 %0, %1" : "=v"(r) : "v"(x)); return r;
}

static __device__ __forceinline__ unsigned cvt_pk_bf16(float lo, float hi) {
    unsigned r;
    asm("v_cvt_pk_bf16_f32 %0, %1, %2" : "=v"(r) : "v"(lo), "v"(hi));
    return r;
}

static __device__ __forceinline__ void store_out(float* p, float v) { *p = v; }
static __device__ __forceinline__ void store_out(unsigned short* p, float v) { *p = f2bf(v); }

// ---------------- prep: fp32 -> bf16 flat convert ---------------------------
__global__ __launch_bounds__(256) void conv_f32_bf16(
    const float* __restrict__ in, unsigned short* __restrict__ out, int n8)
{
    const int i = blockIdx.x * 256 + threadIdx.x;
    if (i >= n8) return;
    const float4 a = ((const float4*)in)[i * 2];
    const float4 b = ((const float4*)in)[i * 2 + 1];
    bfrag o;
    o[0] = f2bf(a.x); o[1] = f2bf(a.y); o[2] = f2bf(a.z); o[3] = f2bf(a.w);
    o[4] = f2bf(b.x); o[5] = f2bf(b.y); o[6] = f2bf(b.z); o[7] = f2bf(b.w);
    ((bfrag*)out)[i] = o;
}

// ---------------- prep: [R][C] fp32 -> [C][R] bf16 transpose ----------------
__global__ __launch_bounds__(256) void transpose_f32_bf16(
    const float* __restrict__ in, unsigned short* __restrict__ out, int R, int C)
{
    __shared__ unsigned short t[64][72];
    const int tid = threadIdx.x;
    const int c0 = blockIdx.x * 64, r0 = blockIdx.y * 64;
    #pragma unroll
    for (int i = 0; i < 4; ++i) {
        const int r = (tid >> 4) + i * 16;
        const int c = (tid & 15) * 4;
        const float4 v = *(const float4*)&in[(size_t)(r0 + r) * C + c0 + c];
        t[c + 0][r] = f2bf(v.x);
        t[c + 1][r] = f2bf(v.y);
        t[c + 2][r] = f2bf(v.z);
        t[c + 3][r] = f2bf(v.w);
    }
    __syncthreads();
    #pragma unroll
    for (int i = 0; i < 2; ++i) {
        const int c = (tid >> 3) + i * 32;
        const int r = (tid & 7) * 8;
        *(bfrag*)&out[(size_t)(c0 + c) * R + r0 + r] = *(const bfrag*)&t[c][r];
    }
}

// ---------------- prep: V part of qkv -> vT[bh*64 + d][s]; zero queue -------
__global__ __launch_bounds__(256) void transpose_v(
    const unsigned short* __restrict__ qkvb, unsigned short* __restrict__ vT,
    int* __restrict__ qctr)
{
    if (blockIdx.x == 0 && blockIdx.y == 0 && threadIdx.x < 8)
        qctr[threadIdx.x] = 0;
    __shared__ unsigned short t[64][76];
    const int bh = blockIdx.y, h = bh % HN, b = bh / HN;
    const int s0 = blockIdx.x * 64;
    const int tid = threadIdx.x;
    #pragma unroll
    for (int it = 0; it < 2; ++it) {
        const int slot = it * 256 + tid;
        const int r = slot >> 3, c8 = slot & 7;
        const bfrag v = *(const bfrag*)(
            qkvb + ((size_t)(b * SEQ + s0 + r)) * QR + 2 * BDIM + h * HDIM + c8 * 8);
        #pragma unroll
        for (int j = 0; j < 8; ++j) t[c8 * 8 + j][r] = (unsigned short)v[j];
    }
    __syncthreads();
    #pragma unroll
    for (int it = 0; it < 2; ++it) {
        const int slot = it * 256 + tid;
        const int d = slot >> 3, s8 = slot & 7;
        bfrag o;
        #pragma unroll
        for (int j = 0; j < 8; ++j) o[j] = (short)t[d][s8 * 8 + j];
        *(bfrag*)(vT + ((size_t)bh * HDIM + d) * SEQ + s0 + s8 * 8) = o;
    }
}

// ---------------- bf16 MFMA GEMM: C[M,N] = A[M,K] @ Bt[N,K]^T + bias --------
template <typename OUTT>
__global__ __launch_bounds__(256) void gemm_mfma_bt(
    const unsigned short* __restrict__ A,   // [M][K] bf16
    const unsigned short* __restrict__ Bt,  // [N][K] bf16
    const float* __restrict__ bias,
    OUTT* __restrict__ C, int M, int N, int K)
{
    __shared__ unsigned short As[128 * 64];
    __shared__ unsigned short Bs[128 * 64];

    const int tid  = threadIdx.x;
    const int lane = tid & 63;
    const int wid  = tid >> 6;
    const int l15  = lane & 15;
    const int l4   = lane >> 4;
    const int m0 = blockIdx.y * 128;
    const int n0 = blockIdx.x * 128;
    const int wm = (wid >> 1) * 64;
    const int wn = (wid & 1) * 64;

    f32x4 acc[4][4] = {};

    for (int k0 = 0; k0 < K; k0 += 64) {
        __syncthreads();
        #pragma unroll
        for (int i = 0; i < 4; ++i) {
            const int row = wid * 32 + i * 8 + (lane >> 3);
            const int ck  = (((lane & 7) ^ (row & 7)) * 8);
            __builtin_amdgcn_global_load_lds(
                (const __attribute__((address_space(1))) void*)(A + (size_t)(m0 + row) * K + k0 + ck),
                (__attribute__((address_space(3))) void*)(As + (wid * 4 + i) * 512),
                16, 0, 0);
            __builtin_amdgcn_global_load_lds(
                (const __attribute__((address_space(1))) void*)(Bt + (size_t)(n0 + row) * K + k0 + ck),
                (__attribute__((address_space(3))) void*)(Bs + (wid * 4 + i) * 512),
                16, 0, 0);
        }
        __syncthreads();

        #pragma unroll
        for (int ks = 0; ks < 2; ++ks) {
            bfrag af[4], bfv[4];
            #pragma unroll
            for (int mi = 0; mi < 4; ++mi) {
                const int row = wm + mi * 16 + l15;
                const int ch  = (ks * 4 + l4) ^ (row & 7);
                af[mi] = *(const bfrag*)(As + row * 64 + ch * 8);
            }
            #pragma unroll
            for (int ni = 0; ni < 4; ++ni) {
                const int row = wn + ni * 16 + l15;
                const int ch  = (ks * 4 + l4) ^ (row & 7);
                bfv[ni] = *(const bfrag*)(Bs + row * 64 + ch * 8);
            }
            #pragma unroll
            for (int mi = 0; mi < 4; ++mi)
                #pragma unroll
                for (int ni = 0; ni < 4; ++ni)
                    acc[mi][ni] = __builtin_amdgcn_mfma_f32_16x16x32_bf16(
                        af[mi], bfv[ni], acc[mi][ni], 0, 0, 0);
        }
    }

    #pragma unroll
    for (int mi = 0; mi < 4; ++mi)
        #pragma unroll
        for (int ni = 0; ni < 4; ++ni) {
            const int n = n0 + wn + ni * 16 + l15;
            const float bv = bias[n];
            #pragma unroll
            for (int r = 0; r < 4; ++r) {
                const int m = m0 + wm + mi * 16 + l4 * 4 + r;
                store_out(C + (size_t)m * N + n, acc[mi][ni][r] + bv);
            }
        }
}

// ---------------- MFMA flash attention (deferred-PV pipeline) ---------------
// Swapped QK^T, in-reg softmax; PV of tile t-1 issued back-to-back with QK of
// tile t (register-only), V fragments register-resident across steps.
#define C2 0.18033688011112042f   /* 0.125 * log2(e) */
#define THR 8.0f

__global__ __launch_bounds__(256, 4) void attn_flash_mfma(
    const unsigned short* __restrict__ qkv,
    const unsigned short* __restrict__ vT,
    unsigned short* __restrict__ yatt,
    int* __restrict__ qctr)
{
    __shared__ unsigned short Ks[2][64 * 64];   // [k][d] swizzled
    __shared__ unsigned short Vs[2][64 * 64];   // [d][k] swizzled

    const int hint = blockIdx.x & 7;
    const int tid  = threadIdx.x;
    const int lane = tid & 63;
    const int wid  = tid >> 6;
    const int l15  = lane & 15;
    const int l4   = lane >> 4;

    for (;;) {
        __syncthreads();                       // prev item's compute done
        if (tid == 0) *(int*)Ks = atomicAdd(&qctr[hint], 1);
        __syncthreads();
        const int it = *(const int*)Ks;
        if (it >= 192) break;
        __syncthreads();                       // all read `it` before staging
        const int bh = hint * 6 + (it % 6);
        const int qt = 31 - (it / 6);
        const int h = bh % HN, b = bh / HN;
        const int q0 = qt * 64;

        const size_t baserow = (size_t)b * SEQ;
        const unsigned short* kg = qkv + baserow * QR + BDIM + h * HDIM;
        const unsigned short* vg = vT + (size_t)bh * HDIM * SEQ;

        // Q fragments (B-operand): Q[q = q0+wid*16+l15][d = ks*32 + l4*8 + j]
        const unsigned short* qrow =
            qkv + (baserow + q0 + wid * 16 + l15) * QR + h * HDIM;
        const bfrag qf0 = *(const bfrag*)(qrow + l4 * 8);
        const bfrag qf1 = *(const bfrag*)(qrow + 32 + l4 * 8);

        f32x4 acc_o[4] = {};
        float m = -3.0e38f;
        float l = 0.f;

        // pipeline state: P(t-1) and V(t-1) fragments (zero => PV adds 0)
        union { bfrag f; unsigned u[4]; } pf[2];
        bfrag vr[2][4];
        #pragma unroll
        for (int ks = 0; ks < 2; ++ks) {
            #pragma unroll
            for (int i = 0; i < 4; ++i) pf[ks].u[i] = 0u;
            #pragma unroll
            for (int ds = 0; ds < 4; ++ds)
                #pragma unroll
                for (int j = 0; j < 8; ++j) vr[ks][ds][j] = 0;
        }

        // prologue stage tile 0
        #pragma unroll
        for (int i = 0; i < 2; ++i) {
            const int row = wid * 16 + i * 8 + (lane >> 3);
            const int ck  = (((lane & 7) ^ (row & 7)) * 8);
            __builtin_amdgcn_global_load_lds(
                (const __attribute__((address_space(1))) void*)(kg + (size_t)row * QR + ck),
                (__attribute__((address_space(3))) void*)(&Ks[0][row * 64]),
                16, 0, 0);
            __builtin_amdgcn_global_load_lds(
                (const __attribute__((address_space(1))) void*)(vg + (size_t)row * SEQ + ck),
                (__attribute__((address_space(3))) void*)(&Vs[0][row * 64]),
                16, 0, 0);
        }
        __syncthreads();

        int buf = 0;
        for (int kt = 0;;) {
            if (kt < qt) {                    // async prefetch next tile
                const int k0n = (kt + 1) * 64;
                #pragma unroll
                for (int i = 0; i < 2; ++i) {
                    const int row = wid * 16 + i * 8 + (lane >> 3);
                    const int ck  = (((lane & 7) ^ (row & 7)) * 8);
                    __builtin_amdgcn_global_load_lds(
                        (const __attribute__((address_space(1))) void*)(kg + (size_t)(k0n + row) * QR + ck),
                        (__attribute__((address_space(3))) void*)(&Ks[buf ^ 1][row * 64]),
                        16, 0, 0);
                    __builtin_amdgcn_global_load_lds(
                        (const __attribute__((address_space(1))) void*)(vg + (size_t)row * SEQ + k0n + ck),
                        (__attribute__((address_space(3))) void*)(&Vs[buf ^ 1][row * 64]),
                        16, 0, 0);
                }
            }

            const unsigned short* Kb = Ks[buf];
            const unsigned short* Vb = Vs[buf];

            // ---- MFMA cluster: S^T = K Q^T (tile kt)  +  O += P V (tile kt-1)
            f32x4 s[4] = {};
            __builtin_amdgcn_s_setprio(1);
            #pragma unroll
            for (int ks = 0; ks < 2; ++ks) {
                const bfrag qk = ks ? qf1 : qf0;
                #pragma unroll
                for (int cs = 0; cs < 4; ++cs) {
                    const int row = cs * 16 + l15;
                    const int ch  = (ks * 4 + l4) ^ (row & 7);
                    const bfrag kf = *(const bfrag*)(Kb + row * 64 + ch * 8);
                    s[cs] = __builtin_amdgcn_mfma_f32_16x16x32_bf16(kf, qk, s[cs], 0, 0, 0);
                }
            }
            #pragma unroll
            for (int ks = 0; ks < 2; ++ks)
                #pragma unroll
                for (int ds = 0; ds < 4; ++ds)
                    acc_o[ds] = __builtin_amdgcn_mfma_f32_16x16x32_bf16(
                        pf[ks].f, vr[ks][ds], acc_o[ds], 0, 0, 0);
            __builtin_amdgcn_s_setprio(0);

            // ---- refill V regs with tile kt (for PV next step / epilogue) ----
            #pragma unroll
            for (int ks = 0; ks < 2; ++ks)
                #pragma unroll
                for (int ds = 0; ds < 4; ++ds) {
                    const int vrow = ds * 16 + l15;
                    const int vch  = (ks * 4 + l4) ^ (vrow & 7);
                    vr[ks][ds] = *(const bfrag*)(Vb + vrow * 64 + vch * 8);
                }

            // ---- causal mask on diagonal tile (k > q) ----
            if (kt == qt) {
                #pragma unroll
                for (int cs = 0; cs < 4; ++cs)
                    #pragma unroll
                    for (int r = 0; r < 4; ++r)
                        if (cs * 16 + l4 * 4 + r > wid * 16 + l15)
                            s[cs][r] = -3.0e38f;
            }

            // ---- lane-local online softmax (row q=l15; k spread over l4) ----
            float mx = s[0][0];
            #pragma unroll
            for (int cs = 0; cs < 4; ++cs)
                #pragma unroll
                for (int r = 0; r < 4; ++r) mx = fmaxf(mx, s[cs][r]);
            mx = fmaxf(mx, __shfl_xor(mx, 16));
            mx = fmaxf(mx, __shfl_xor(mx, 32));
            const float mx2 = mx * C2;

            if (!__all(mx2 <= m + THR)) {     // rescale path (acc is PV-complete
                const float mnew = fmaxf(m, mx2);   // through kt-1 at this point)
                const float fac  = fexp2(m - mnew);
                m = mnew;
                l *= fac;
                #pragma unroll
                for (int r = 0; r < 4; ++r) {
                    const float fr = __shfl(fac, (lane & 48) | (l4 * 4 + r));
                    #pragma unroll
                    for (int ds = 0; ds < 4; ++ds) acc_o[ds][r] *= fr;
                }
            }

            float rsum = 0.f;
            #pragma unroll
            for (int cs = 0; cs < 4; ++cs)
                #pragma unroll
                for (int r = 0; r < 4; ++r) {
                    const float pv = fexp2(fmaf(s[cs][r], C2, -m));
                    s[cs][r] = pv;
                    rsum += pv;
                }
            rsum += __shfl_xor(rsum, 16);
            rsum += __shfl_xor(rsum, 32);
            l += rsum;

            // ---- P -> bf16 pairs, redistribute to PV A-fragment in-reg ----
            unsigned pk[4][2];
            #pragma unroll
            for (int cs = 0; cs < 4; ++cs) {
                pk[cs][0] = cvt_pk_bf16(s[cs][0], s[cs][1]);
                pk[cs][1] = cvt_pk_bf16(s[cs][2], s[cs][3]);
            }
            #pragma unroll
            for (int ks = 0; ks < 2; ++ks)
                #pragma unroll
                for (int i = 0; i < 2; ++i) {
                    const unsigned A  = pk[ks * 2][i];
                    const unsigned B  = pk[ks * 2 + 1][i];
                    const unsigned Ax = __shfl_xor(A, 32);
                    const unsigned Bx = __shfl_xor(B, 32);
                    const unsigned P1 = (l4 < 2) ? A : Bx;
                    const unsigned P2 = (l4 < 2) ? Ax : B;
                    const unsigned S1 = __shfl_xor(P1, 16);
                    const unsigned S2 = __shfl_xor(P2, 16);
                    pf[ks].u[i]     = (l4 & 1) ? S2 : P1;
                    pf[ks].u[2 + i] = (l4 & 1) ? P2 : S1;
                }

            if (kt == qt) break;
            __syncthreads();      // drains own gload_lds + all waves done
            buf ^= 1; ++kt;
        }

        // ---- epilogue: PV of final tile ----
        #pragma unroll
        for (int ks = 0; ks < 2; ++ks)
            #pragma unroll
            for (int ds = 0; ds < 4; ++ds)
                acc_o[ds] = __builtin_amdgcn_mfma_f32_16x16x32_bf16(
                    pf[ks].f, vr[ks][ds], acc_o[ds], 0, 0, 0);

        // ---- normalize + store (bf16); l lives at lane with l15 == q ----
        const float inv = 1.f / l;
        #pragma unroll
        for (int r = 0; r < 4; ++r) {
            const float invr = __shfl(inv, (lane & 48) | (l4 * 4 + r));
            unsigned short* orow =
                yatt + (baserow + q0 + wid * 16 + l4 * 4 + r) * BDIM + h * HDIM;
            #pragma unroll
            for (int ds = 0; ds < 4; ++ds)
                orow[ds * 16 + l15] = f2bf(acc_o[ds][r] * invr);
        }
    }
}

// ---------------- launch -----------------------------------------------------
extern "C" void kernel_launch(void* const* d_in, const int* in_sizes, int n_in,
                              void* d_out, int out_size, void* d_ws, size_t ws_size,
                              hipStream_t stream)
{
    const float* x      = (const float*)d_in[0];
    const float* w_qkv  = (const float*)d_in[1];
    const float* b_qkv  = (const float*)d_in[2];
    const float* w_proj = (const float*)d_in[3];
    const float* b_proj = (const float*)d_in[4];
    float* out = (float*)d_out;

    unsigned short* xb   = (unsigned short*)d_ws;                 // [8192][768]
    unsigned short* qkvb = xb   + (size_t)MTOT * BDIM;            // [8192][2304]
    unsigned short* yatt = qkvb + (size_t)MTOT * 3 * BDIM;        // [8192][768]
    unsigned short* wqT  = yatt + (size_t)MTOT * BDIM;            // [2304][768]
    unsigned short* wpT  = wqT  + (size_t)3 * BDIM * BDIM;        // [768][768]
    int*            qctr = (int*)(wpT + (size_t)BDIM * BDIM);     // [8]
    unsigned short* vT   = xb;   // reuse: xb dead after GEMM1    // [48*64][2048]

    // prep
    conv_f32_bf16<<<(MTOT * BDIM / 8 + 255) / 256, 256, 0, stream>>>(
        x, xb, MTOT * BDIM / 8);
    transpose_f32_bf16<<<dim3(3 * BDIM / 64, BDIM / 64), 256, 0, stream>>>(
        w_qkv, wqT, BDIM, 3 * BDIM);
    transpose_f32_bf16<<<dim3(BDIM / 64, BDIM / 64), 256, 0, stream>>>(
        w_proj, wpT, BDIM, BDIM);

    // qkv = x @ w_qkv + b_qkv   (bf16 out)
    gemm_mfma_bt<unsigned short><<<dim3(3 * BDIM / 128, MTOT / 128), 256, 0, stream>>>(
        xb, wqT, b_qkv, qkvb, MTOT, 3 * BDIM, BDIM);

    // V -> vT (overwrites xb) + zero the work queues
    transpose_v<<<dim3(SEQ / 64, BATCH * HN), 256, 0, stream>>>(qkvb, vT, qctr);

    // flash attention (work-stealing queues, 4 blocks/CU)
    attn_flash_mfma<<<dim3(1024), 256, 0, stream>>>(qkvb, vT, yatt, qctr);

    // out = yatt @ w_proj + b_proj   (fp32 out)
    gemm_mfma_bt<float><<<dim3(BDIM / 128, MTOT / 128), 256, 0, stream>>>(
        yatt, wpT, b_proj, out, MTOT, BDIM, BDIM);
}